// Round 21
// baseline (115.733 us; speedup 1.0000x reference)
//
#include <hip/hip_runtime.h>
#include <hip/hip_bf16.h>

#define NEG_SLOPE 0.2f
#define ROWB 320      // node row: ft bf16[128] | y bf16[16] | (pad)
#define BSLOT 80      // bucket slots per node (max padded degree ~48)
#define NSUBMAX 256   // max sub-bins (N <= 65536)
#define QCAP2 32      // binA2 LDS queue depth per sub-bin (mean ~21)
#define SUBSHIFT 8    // sub-bin = dst >> 8 (256 nodes)
#define SUBCAP 5888   // per-sub-bin global queue capacity (mean 5120 + 11 sigma)

typedef unsigned short u16;
typedef unsigned int u32;
typedef unsigned long long u64;
typedef __attribute__((ext_vector_type(8))) short bf16x8;
typedef __attribute__((ext_vector_type(4))) float f32x4;

__device__ __forceinline__ u16 f32_to_bf16(float x) {
    u32 u = __float_as_uint(x);
    u32 r = u + 0x7fffu + ((u >> 16) & 1u);  // round-to-nearest-even
    return (u16)(r >> 16);
}
__device__ __forceinline__ u32 bf16pair(float a, float b) {
    return (u32)f32_to_bf16(a) | ((u32)f32_to_bf16(b) << 16);
}
__device__ __forceinline__ float bflo(u32 u) { return __uint_as_float(u << 16); }
__device__ __forceinline__ float bfhi(u32 u) { return __uint_as_float(u & 0xffff0000u); }

// ---------------- k_f1: binA2 (blocks < binAB) + MFMA proj64 ---------------
__global__ __launch_bounds__(256) void k_f1(
    const float* __restrict__ feat, const float* __restrict__ fc_w,
    const float* __restrict__ y, const float* __restrict__ attn_l,
    const float* __restrict__ attn_r, char* __restrict__ comb,
    float* __restrict__ elr, const int* __restrict__ src,
    const int* __restrict__ dst, u32* __restrict__ subQ,
    int* __restrict__ subCursor, int N, int E, int nSub, int binAB) {
    __shared__ u16 w16[16384];     // 32KB: fc_w B-frag / binA2 q (256x32 u32)
    __shared__ u16 f16[64 * 136];  // 17KB: feat bf16 / binA2 lcnt+lbase
    int t = threadIdx.x;

    if ((int)blockIdx.x < binAB) {
        // ----- binA2: bin 4096 edges into 256-node sub-bins via LDS -----
        u32* q = (u32*)w16;            // 256 bins x QCAP2
        int* lcnt = (int*)f16;
        int* lbase = lcnt + 256;
        lcnt[t] = 0;
        __syncthreads();
        int base = blockIdx.x * 4096;
#define PUSH(dd, sv)                                                      \
        {                                                                 \
            u32 bin_ = (u32)(dd) >> SUBSHIFT;                             \
            u32 pair_ = ((u32)(dd) << 16) | ((u32)(sv) & 0xffffu);        \
            int p_ = atomicAdd(&lcnt[bin_], 1);                           \
            if (p_ < QCAP2) q[bin_ * QCAP2 + p_] = pair_;                 \
            else {                                                        \
                int gp_ = atomicAdd(&subCursor[bin_], 1);                 \
                if (gp_ < SUBCAP) subQ[(size_t)bin_ * SUBCAP + gp_] = pair_; \
            }                                                             \
        }
        for (int it = 0; it < 4; ++it) {
            int i = base + it * 1024 + t * 4;
            if (i + 4 <= E) {
                int4 d = *(const int4*)(dst + i);
                int4 s = *(const int4*)(src + i);
                PUSH(d.x, s.x); PUSH(d.y, s.y); PUSH(d.z, s.z); PUSH(d.w, s.w);
            } else {
                for (int k = 0; k < 4 && i + k < E; ++k) PUSH(dst[i + k], src[i + k]);
            }
        }
#undef PUSH
        __syncthreads();
        if (t < nSub) {
            int c = min(lcnt[t], QCAP2);
            lbase[t] = atomicAdd(&subCursor[t], c);
        }
        __syncthreads();
        int lane = t & 63, wv = t >> 6;
        for (int b = wv; b < nSub; b += 4) {
            int c = min(lcnt[b], QCAP2);
            if (lane < c) {
                int gp = lbase[b] + lane;
                if (gp < SUBCAP) subQ[(size_t)b * SUBCAP + gp] = q[b * QCAP2 + lane];
            }
        }
        return;
    }

    // ----- proj: MFMA bf16 GEMM, 64 nodes/block -----
    int pb = (int)blockIdx.x - binAB;
    int n0 = pb * 64;
    if (pb == 0) {                         // sentinel row N
        if (t < 80) ((float*)(comb + (size_t)N * ROWB))[t] = 0.f;
        if (t < 8) elr[(size_t)N * 8 + t] = (t < 4) ? -1e30f : 0.f;
    }

    // stage fc_w -> bf16, pre-swizzled to B-fragment layout:
    // w16[((jt*4+kt)*64 + 16*h + jm)*8 + i] = fc_w[kt*32+8h+i][jt*16+jm]
#pragma unroll
    for (int it = 0; it < 16; ++it) {
        int i = it * 256 + t;              // float4 index: k = i>>5, j = 4*(i&31)
        float4 v = *(const float4*)(fc_w + 4 * i);
        int k = i >> 5, jq = i & 31;
        int kt = k >> 5, h2 = (k >> 3) & 3, i0 = k & 7;
        int jt = jq >> 2, jm0 = (jq & 3) * 4;
        int base = ((jt * 4 + kt) * 64 + 16 * h2 + jm0) * 8 + i0;
        w16[base] = f32_to_bf16(v.x);
        w16[base + 8] = f32_to_bf16(v.y);
        w16[base + 16] = f32_to_bf16(v.z);
        w16[base + 24] = f32_to_bf16(v.w);
    }
    // stage feat -> bf16 rows (row pitch 136 -> 16B-aligned fragments)
#pragma unroll
    for (int it = 0; it < 8; ++it) {
        int i = it * 256 + t;
        int n = i >> 5, q4 = (i & 31) * 4;
        float4 v = make_float4(0.f, 0.f, 0.f, 0.f);
        if (n0 + n < N) v = *(const float4*)(feat + (size_t)(n0 + n) * 128 + q4);
        *(uint2*)(f16 + n * 136 + q4) = make_uint2(bf16pair(v.x, v.y), bf16pair(v.z, v.w));
    }
#pragma unroll
    for (int it = 0; it < 4; ++it) {       // y cast
        int i = it * 256 + t;
        int n = i >> 4, col = i & 15;
        if (n0 + n < N) {
            float yv = y[(size_t)(n0 + n) * 16 + col];
            *(u16*)(comb + (size_t)(n0 + n) * ROWB + 256 + 2 * col) = f32_to_bf16(yv);
        }
    }
    __syncthreads();

    int wv2 = t >> 6, l = t & 63;
    int m = l & 15, h = l >> 4;

    f32x4 acc[8];
#pragma unroll
    for (int jt = 0; jt < 8; ++jt) acc[jt] = (f32x4){0.f, 0.f, 0.f, 0.f};

    const u16* arow = f16 + (16 * wv2 + m) * 136 + 8 * h;
#pragma unroll
    for (int kt = 0; kt < 4; ++kt) {
        uint4 av = *(const uint4*)(arow + kt * 32);
        bf16x8 a = __builtin_bit_cast(bf16x8, av);
#pragma unroll
        for (int jt = 0; jt < 8; ++jt) {
            uint4 bv = *(const uint4*)(w16 + ((jt * 4 + kt) * 64 + l) * 8);
            bf16x8 bfr = __builtin_bit_cast(bf16x8, bv);
            acc[jt] = __builtin_amdgcn_mfma_f32_16x16x32_bf16(a, bfr, acc[jt], 0, 0, 0);
        }
    }

    // write C (bf16) over this wave's own feat rows (wave-private slice)
#pragma unroll
    for (int jt = 0; jt < 8; ++jt)
#pragma unroll
        for (int r = 0; r < 4; ++r)
            f16[(16 * wv2 + 4 * h + r) * 136 + 16 * jt + m] = f32_to_bf16(acc[jt][r]);
    __syncthreads();

    // epilogue: comb ft write + el/er (8-lane-group reduce) -> dense elr
    int c = t & 31;   // col quad 4c..4c+3, head = c>>3
    int g = t >> 5;   // nodes 8g..8g+7
    float4 al4 = *(const float4*)(attn_l + 4 * c);
    float4 ar4 = *(const float4*)(attn_r + 4 * c);

#pragma unroll
    for (int j = 0; j < 8; ++j) {
        int n = n0 + 8 * g + j;
        bool ok = n < N;
        uint2 cv = *(const uint2*)(f16 + (8 * g + j) * 136 + 4 * c);
        float f0 = bflo(cv.x), f1 = bfhi(cv.x), f2 = bflo(cv.y), f3 = bfhi(cv.y);
        if (ok) *(uint2*)(comb + (size_t)n * ROWB + 8 * c) = cv;
        float p = f0 * al4.x + f1 * al4.y + f2 * al4.z + f3 * al4.w;
        float q = f0 * ar4.x + f1 * ar4.y + f2 * ar4.z + f3 * ar4.w;
#pragma unroll
        for (int off = 1; off < 8; off <<= 1) {
            p += __shfl_xor(p, off);
            q += __shfl_xor(q, off);
        }
        if (ok && (c & 7) == 0) {
            elr[(size_t)n * 8 + (c >> 3)] = p;
            elr[(size_t)n * 8 + 4 + (c >> 3)] = q;
        }
    }
}

// ---------------- k_passC: exclusive-owner placement, no global atomics ----
__global__ __launch_bounds__(256) void k_passC(
    const u32* __restrict__ subQ, const int* __restrict__ subCursor,
    int* __restrict__ cnt, u16* __restrict__ ss, int N) {
    __shared__ int hist[256];
    __shared__ int cur[256];
    int t = threadIdx.x;
    int b = blockIdx.x;
    hist[t] = 0;
    cur[t] = 0;
    __syncthreads();
    int n_b = min(subCursor[b], SUBCAP);
    const u32* qb = subQ + (size_t)b * SUBCAP;

    for (int i = t * 4; i < n_b; i += 1024) {
        if (i + 4 <= n_b) {
            uint4 p4 = *(const uint4*)(qb + i);
            atomicAdd(&hist[(p4.x >> 16) & 255], 1);
            atomicAdd(&hist[(p4.y >> 16) & 255], 1);
            atomicAdd(&hist[(p4.z >> 16) & 255], 1);
            atomicAdd(&hist[(p4.w >> 16) & 255], 1);
        } else {
            for (int k = i; k < n_b; ++k) atomicAdd(&hist[(qb[k] >> 16) & 255], 1);
        }
    }
    __syncthreads();
    int node = (b << SUBSHIFT) + t;
    if (node < N) cnt[node] = min(hist[t], BSLOT);

    for (int i = t * 4; i < n_b; i += 1024) {
        if (i + 4 <= n_b) {
            uint4 p4 = *(const uint4*)(qb + i);
            u32 pa[4] = {p4.x, p4.y, p4.z, p4.w};
#pragma unroll
            for (int k = 0; k < 4; ++k) {
                int r = (pa[k] >> 16) & 255;
                int p = atomicAdd(&cur[r], 1);
                if (p < BSLOT)
                    ss[(size_t)(pa[k] >> 16) * BSLOT + p] = (u16)(pa[k] & 0xffffu);
            }
        } else {
            for (int k = i; k < n_b; ++k) {
                u32 pr = qb[k];
                int r = (pr >> 16) & 255;
                int p = atomicAdd(&cur[r], 1);
                if (p < BSLOT)
                    ss[(size_t)(pr >> 16) * BSLOT + p] = (u16)(pr & 0xffffu);
            }
        }
    }
}

// ---------------- k_agg: one wave/node; 2 edges/step, uint4 gathers -------
__global__ __launch_bounds__(256) void k_agg(
    const char* __restrict__ comb, const float* __restrict__ elr,
    const float* __restrict__ bias, const int* __restrict__ cnt,
    const u16* __restrict__ ss, float* __restrict__ rst,
    float* __restrict__ yp, int N) {
    __shared__ float ee_lds[4][256];   // per-wave 1KB slice: [edge][head]
    int w = (int)((blockIdx.x * (size_t)blockDim.x + threadIdx.x) >> 6);
    int lane = threadIdx.x & 63;
    int wv = threadIdx.x >> 6;
    if (w >= N) return;

    int sub = lane & 31;
    int p = lane >> 5;
    bool isft = sub < 16;
    bool isy = (sub >= 16) && (sub < 24);
    int head = isft ? (sub >> 2) : (isy ? ((sub - 16) >> 1) : 0);
    int voff = isft ? 16 * sub : (256 + 16 * ((sub - 16) & 1));

    float4 er4 = *(const float4*)(elr + (size_t)w * 8 + 4);

    int deg = min(cnt[w], BSLOT);
    int degp = min((deg + 7) & ~7, BSLOT);
    int beg = w * BSLOT;

    float acc0 = 0.f, acc1 = 0.f, acc2 = 0.f, acc3 = 0.f;
    float acc4 = 0.f, acc5 = 0.f, acc6 = 0.f, acc7 = 0.f;
    float ssum = 0.f;
    float* my_ee = &ee_lds[wv][0];
    const float* eeL = my_ee + 4 * p + head;

#define LOADS(qq, V, Ee)                                        \
    {                                                           \
        int s0_ = __builtin_amdgcn_readlane(my_s, 2 * (qq));    \
        int s1_ = __builtin_amdgcn_readlane(my_s, 2 * (qq) + 1);\
        int s_ = p ? s1_ : s0_;                                 \
        const char* rb_ = comb + (size_t)s_ * ROWB;             \
        V = *(const uint4*)(rb_ + voff);                        \
        Ee = eeL[8 * (qq)];                                     \
    }
#define COMPS(V, Ee)                                            \
    {                                                           \
        ssum += Ee;                                             \
        acc0 = fmaf(Ee, bflo(V.x), acc0);                       \
        acc1 = fmaf(Ee, bfhi(V.x), acc1);                       \
        acc2 = fmaf(Ee, bflo(V.y), acc2);                       \
        acc3 = fmaf(Ee, bfhi(V.y), acc3);                       \
        acc4 = fmaf(Ee, bflo(V.z), acc4);                       \
        acc5 = fmaf(Ee, bfhi(V.z), acc5);                       \
        acc6 = fmaf(Ee, bflo(V.w), acc6);                       \
        acc7 = fmaf(Ee, bfhi(V.w), acc7);                       \
    }
#define LOAD4A(gg)                                              \
    {                                                           \
        int b4_ = 4 * (gg);                                     \
        LOADS(b4_ + 0, va0, ea0); LOADS(b4_ + 1, va1, ea1);     \
        LOADS(b4_ + 2, va2, ea2); LOADS(b4_ + 3, va3, ea3);     \
    }
#define LOAD4B(gg)                                              \
    {                                                           \
        int b4_ = 4 * (gg);                                     \
        LOADS(b4_ + 0, vb0, eb0); LOADS(b4_ + 1, vb1, eb1);     \
        LOADS(b4_ + 2, vb2, eb2); LOADS(b4_ + 3, vb3, eb3);     \
    }
#define COMP4A { COMPS(va0, ea0); COMPS(va1, ea1); COMPS(va2, ea2); COMPS(va3, ea3); }
#define COMP4B { COMPS(vb0, eb0); COMPS(vb1, eb1); COMPS(vb2, eb2); COMPS(vb3, eb3); }

    for (int off = 0; off < degp; off += 64) {
        int cl = min(64, degp - off);   // multiple of 8
        int my_s = (int)ss[beg + off + lane];
        my_s = (off + lane < deg) ? my_s : N;   // sentinel for pad/garbage slots

        // chunk preamble: lane computes its edge's ee for all 4 heads
        {
            const float4 el4 = *(const float4*)(elr + (size_t)my_s * 8);
            float4 e4;
            e4.x = el4.x + er4.x;
            e4.y = el4.y + er4.y;
            e4.z = el4.z + er4.z;
            e4.w = el4.w + er4.w;
            float4 ee4;
            ee4.x = __expf(fmaxf(e4.x, NEG_SLOPE * e4.x));
            ee4.y = __expf(fmaxf(e4.y, NEG_SLOPE * e4.y));
            ee4.z = __expf(fmaxf(e4.z, NEG_SLOPE * e4.z));
            ee4.w = __expf(fmaxf(e4.w, NEG_SLOPE * e4.w));
            *(float4*)(my_ee + 4 * lane) = ee4;
        }

        int ngr = cl >> 3;   // groups of 4 steps = 8 edges
        uint4 va0, va1, va2, va3, vb0, vb1, vb2, vb3;
        float ea0, ea1, ea2, ea3, eb0, eb1, eb2, eb3;

        LOAD4A(0);
        int q = 0;
        for (; q + 2 <= ngr; q += 2) {
            LOAD4B(q + 1);
            COMP4A;
            if (q + 2 < ngr) LOAD4A(q + 2);
            COMP4B;
        }
        if (q < ngr) COMP4A;
    }
#undef LOADS
#undef COMPS
#undef LOAD4A
#undef LOAD4B
#undef COMP4A
#undef COMP4B

    // combine the two edge-parity halves
    ssum += __shfl_xor(ssum, 32);
    acc0 += __shfl_xor(acc0, 32);
    acc1 += __shfl_xor(acc1, 32);
    acc2 += __shfl_xor(acc2, 32);
    acc3 += __shfl_xor(acc3, 32);
    acc4 += __shfl_xor(acc4, 32);
    acc5 += __shfl_xor(acc5, 32);
    acc6 += __shfl_xor(acc6, 32);
    acc7 += __shfl_xor(acc7, 32);

    float inv = 1.f / fmaxf(ssum, 1e-9f);
    if (p == 0) {
        if (isft) {
            float4 b0 = *(const float4*)(bias + 8 * sub);
            float4 b1 = *(const float4*)(bias + 8 * sub + 4);
            float4 o0 = make_float4(fmaf(acc0, inv, b0.x), fmaf(acc1, inv, b0.y),
                                    fmaf(acc2, inv, b0.z), fmaf(acc3, inv, b0.w));
            float4 o1 = make_float4(fmaf(acc4, inv, b1.x), fmaf(acc5, inv, b1.y),
                                    fmaf(acc6, inv, b1.z), fmaf(acc7, inv, b1.w));
            *(float4*)(rst + (size_t)w * 128 + 8 * sub) = o0;
            *(float4*)(rst + (size_t)w * 128 + 8 * sub + 4) = o1;
        } else if (isy) {
            int yi = sub - 16;
            int hh = yi >> 1, hf = yi & 1;
            float4 o0 = make_float4(acc0 * inv, acc1 * inv, acc2 * inv, acc3 * inv);
            float4 o1 = make_float4(acc4 * inv, acc5 * inv, acc6 * inv, acc7 * inv);
            *(float4*)(yp + (size_t)w * 64 + 16 * hh + 8 * hf) = o0;
            *(float4*)(yp + (size_t)w * 64 + 16 * hh + 8 * hf + 4) = o1;
        }
    }
}

extern "C" void kernel_launch(void* const* d_in, const int* in_sizes, int n_in,
                              void* d_out, int out_size, void* d_ws, size_t ws_size,
                              hipStream_t stream) {
    const float* feat   = (const float*)d_in[0];
    const float* y      = (const float*)d_in[1];
    const float* fc_w   = (const float*)d_in[2];
    const float* attn_l = (const float*)d_in[3];
    const float* attn_r = (const float*)d_in[4];
    const float* bias   = (const float*)d_in[5];
    const int*   src    = (const int*)d_in[6];
    const int*   dst    = (const int*)d_in[7];

    const int N = in_sizes[0] / 128;  // FIN = 128
    const int E = in_sizes[6];

    char* comb = (char*)d_ws;                            // (N+1) * 320 B
    float* elr = (float*)(comb + (size_t)(N + 1) * ROWB);// (N+1) * 8 f32
    int* cnt = (int*)(elr + (size_t)(N + 1) * 8);        // N ints
    int* subCursor = cnt + N;                            // NSUBMAX ints
    u16* ss = (u16*)(subCursor + NSUBMAX);               // BSLOT*N u16
    u32* subQ = (u32*)(ss + (size_t)BSLOT * N);          // nSub * SUBCAP u32

    float* rst = (float*)d_out;                          // N*128
    float* yp = rst + (size_t)N * 128;                   // N*64

    const int nSub = (N + 255) >> SUBSHIFT;              // 196 for N=50000
    const int projB = (N + 63) / 64;
    const int binAB = (E + 4095) / 4096;

    (void)hipMemsetAsync(subCursor, 0, NSUBMAX * sizeof(int), stream);
    k_f1<<<dim3(binAB + projB), dim3(256), 0, stream>>>(
        feat, fc_w, y, attn_l, attn_r, comb, elr, src, dst, subQ, subCursor,
        N, E, nSub, binAB);
    k_passC<<<dim3(nSub), dim3(256), 0, stream>>>(subQ, subCursor, cnt, ss, N);
    k_agg<<<dim3(((size_t)N * 64 + 255) / 256), dim3(256), 0, stream>>>(
        comb, elr, bias, cnt, ss, rst, yp, N);
}

// Round 22
// 108.874 us; speedup vs baseline: 1.0630x; 1.0630x over previous
//
#include <hip/hip_runtime.h>
#include <hip/hip_bf16.h>

#define NEG_SLOPE 0.2f
#define ROWB 320      // node row: ft bf16[128] | y bf16[16] | el f32[4] | er f32[4]
#define BSLOT 96      // bucket slots per node
#define NSUBMAX 256   // max sub-bins (N <= 65536)
#define QCAP2 64      // binA2 LDS queue depth per sub-bin
#define SUBSHIFT 8    // sub-bin = dst >> 8 (256 nodes)
#define SUBCAP 6400   // per-sub-bin global queue capacity

typedef unsigned short u16;
typedef unsigned int u32;
typedef unsigned long long u64;
typedef __attribute__((ext_vector_type(8))) short bf16x8;
typedef __attribute__((ext_vector_type(4))) float f32x4;

__device__ __forceinline__ u16 f32_to_bf16(float x) {
    u32 u = __float_as_uint(x);
    u32 r = u + 0x7fffu + ((u >> 16) & 1u);  // round-to-nearest-even
    return (u16)(r >> 16);
}
__device__ __forceinline__ u32 bf16pair(float a, float b) {
    return (u32)f32_to_bf16(a) | ((u32)f32_to_bf16(b) << 16);
}
__device__ __forceinline__ float bflo(u32 u) { return __uint_as_float(u << 16); }
__device__ __forceinline__ float bfhi(u32 u) { return __uint_as_float(u & 0xffff0000u); }

// ---------------- k_binA2: bin 4096 edges/block into 256-node sub-bins -----
__global__ __launch_bounds__(256) void k_binA2(
    const int* __restrict__ src, const int* __restrict__ dst,
    u32* __restrict__ subQ, int* __restrict__ subCursor, int nSub, int E) {
    __shared__ u32 q[NSUBMAX * QCAP2];       // 64 KB
    __shared__ int lcnt[NSUBMAX], lbase[NSUBMAX];
    int t = threadIdx.x;
    lcnt[t] = 0;
    __syncthreads();
    int base = blockIdx.x * 4096;
#define PUSH(dd, sv)                                                      \
    {                                                                     \
        u32 bin_ = (u32)(dd) >> SUBSHIFT;                                 \
        u32 pair_ = ((u32)(dd) << 16) | ((u32)(sv) & 0xffffu);            \
        int p_ = atomicAdd(&lcnt[bin_], 1);                               \
        if (p_ < QCAP2) q[bin_ * QCAP2 + p_] = pair_;                     \
        else {                                                            \
            int gp_ = atomicAdd(&subCursor[bin_], 1);                     \
            if (gp_ < SUBCAP) subQ[(size_t)bin_ * SUBCAP + gp_] = pair_;  \
        }                                                                 \
    }
    for (int it = 0; it < 4; ++it) {
        int i = base + it * 1024 + t * 4;
        if (i + 4 <= E) {
            int4 d = *(const int4*)(dst + i);
            int4 s = *(const int4*)(src + i);
            PUSH(d.x, s.x); PUSH(d.y, s.y); PUSH(d.z, s.z); PUSH(d.w, s.w);
        } else {
            for (int k = 0; k < 4 && i + k < E; ++k) PUSH(dst[i + k], src[i + k]);
        }
    }
#undef PUSH
    __syncthreads();
    if (t < nSub) {
        int c = min(lcnt[t], QCAP2);
        lbase[t] = atomicAdd(&subCursor[t], c);
    }
    __syncthreads();
    int lane = t & 63, wv = t >> 6;
    for (int b = wv; b < nSub; b += 4) {
        int c = min(lcnt[b], QCAP2);
        if (lane < c) {
            int gp = lbase[b] + lane;
            if (gp < SUBCAP) subQ[(size_t)b * SUBCAP + gp] = q[b * QCAP2 + lane];
        }
    }
}

// ---------------- k_fused: passC scatter (blocks < nSub) + MFMA proj64 -----
__global__ __launch_bounds__(256) void k_fused(
    const float* __restrict__ feat, const float* __restrict__ fc_w,
    const float* __restrict__ y, const float* __restrict__ attn_l,
    const float* __restrict__ attn_r, char* __restrict__ comb,
    const u32* __restrict__ subQ, const int* __restrict__ subCursor,
    int* __restrict__ cnt, u16* __restrict__ ss, int N, int nSub) {
    __shared__ u16 w16[16384];     // 32KB: fc_w bf16, B-fragment swizzled
    __shared__ u16 f16[64 * 136];  // 17KB: feat bf16 rows -> C bf16 rows
    __shared__ int hist[256];      // passC
    __shared__ int cur[256];       // passC
    int t = threadIdx.x;

    if ((int)blockIdx.x < nSub) {
        // ----- passC: exclusive-owner placement, zero global atomics -----
        int b = blockIdx.x;
        hist[t] = 0;
        cur[t] = 0;
        __syncthreads();
        int n_b = min(subCursor[b], SUBCAP);
        const u32* qb = subQ + (size_t)b * SUBCAP;

        for (int i = t * 4; i < n_b; i += 1024) {
            if (i + 4 <= n_b) {
                uint4 p4 = *(const uint4*)(qb + i);
                atomicAdd(&hist[(p4.x >> 16) & 255], 1);
                atomicAdd(&hist[(p4.y >> 16) & 255], 1);
                atomicAdd(&hist[(p4.z >> 16) & 255], 1);
                atomicAdd(&hist[(p4.w >> 16) & 255], 1);
            } else {
                for (int k = i; k < n_b; ++k) atomicAdd(&hist[(qb[k] >> 16) & 255], 1);
            }
        }
        __syncthreads();
        int node = (b << SUBSHIFT) + t;
        if (node < N) cnt[node] = min(hist[t], BSLOT);

        for (int i = t * 4; i < n_b; i += 1024) {
            if (i + 4 <= n_b) {
                uint4 p4 = *(const uint4*)(qb + i);
                u32 pa[4] = {p4.x, p4.y, p4.z, p4.w};
#pragma unroll
                for (int k = 0; k < 4; ++k) {
                    int r = (pa[k] >> 16) & 255;
                    int p = atomicAdd(&cur[r], 1);
                    if (p < BSLOT)
                        ss[(size_t)(pa[k] >> 16) * BSLOT + p] = (u16)(pa[k] & 0xffffu);
                }
            } else {
                for (int k = i; k < n_b; ++k) {
                    u32 pr = qb[k];
                    int r = (pr >> 16) & 255;
                    int p = atomicAdd(&cur[r], 1);
                    if (p < BSLOT)
                        ss[(size_t)(pr >> 16) * BSLOT + p] = (u16)(pr & 0xffffu);
                }
            }
        }
        return;
    }

    // ----- proj: MFMA bf16 GEMM, 64 nodes/block -----
    int pb = (int)blockIdx.x - nSub;
    int n0 = pb * 64;
    if (pb == 0 && t < 80) {              // sentinel comb row N
        float* srow = (float*)(comb + (size_t)N * ROWB);
        srow[t] = (t >= 72 && t < 76) ? -1e30f : 0.f;
    }

    // stage fc_w -> bf16, pre-swizzled to B-fragment layout:
    // w16[((jt*4+kt)*64 + 16*h + jm)*8 + i] = fc_w[kt*32+8h+i][jt*16+jm]
#pragma unroll
    for (int it = 0; it < 16; ++it) {
        int i = it * 256 + t;             // float4 index: k = i>>5, j = 4*(i&31)
        float4 v = *(const float4*)(fc_w + 4 * i);
        int k = i >> 5, jq = i & 31;
        int kt = k >> 5, h2 = (k >> 3) & 3, i0 = k & 7;
        int jt = jq >> 2, jm0 = (jq & 3) * 4;
        int base = ((jt * 4 + kt) * 64 + 16 * h2 + jm0) * 8 + i0;
        w16[base] = f32_to_bf16(v.x);
        w16[base + 8] = f32_to_bf16(v.y);
        w16[base + 16] = f32_to_bf16(v.z);
        w16[base + 24] = f32_to_bf16(v.w);
    }
    // stage feat -> bf16 rows (row pitch 136 -> 16B-aligned fragments)
#pragma unroll
    for (int it = 0; it < 8; ++it) {
        int i = it * 256 + t;
        int n = i >> 5, q4 = (i & 31) * 4;
        float4 v = make_float4(0.f, 0.f, 0.f, 0.f);
        if (n0 + n < N) v = *(const float4*)(feat + (size_t)(n0 + n) * 128 + q4);
        *(uint2*)(f16 + n * 136 + q4) = make_uint2(bf16pair(v.x, v.y), bf16pair(v.z, v.w));
    }
#pragma unroll
    for (int it = 0; it < 4; ++it) {      // y cast
        int i = it * 256 + t;
        int n = i >> 4, col = i & 15;
        if (n0 + n < N) {
            float yv = y[(size_t)(n0 + n) * 16 + col];
            *(u16*)(comb + (size_t)(n0 + n) * ROWB + 256 + 2 * col) = f32_to_bf16(yv);
        }
    }
    __syncthreads();

    int wv2 = t >> 6, l = t & 63;
    int m = l & 15, h = l >> 4;

    f32x4 acc[8];
#pragma unroll
    for (int jt = 0; jt < 8; ++jt) acc[jt] = (f32x4){0.f, 0.f, 0.f, 0.f};

    const u16* arow = f16 + (16 * wv2 + m) * 136 + 8 * h;
#pragma unroll
    for (int kt = 0; kt < 4; ++kt) {
        uint4 av = *(const uint4*)(arow + kt * 32);
        bf16x8 a = __builtin_bit_cast(bf16x8, av);
#pragma unroll
        for (int jt = 0; jt < 8; ++jt) {
            uint4 bv = *(const uint4*)(w16 + ((jt * 4 + kt) * 64 + l) * 8);
            bf16x8 bfr = __builtin_bit_cast(bf16x8, bv);
            acc[jt] = __builtin_amdgcn_mfma_f32_16x16x32_bf16(a, bfr, acc[jt], 0, 0, 0);
        }
    }

    // write C (bf16) over this wave's own feat rows (wave-private slice)
#pragma unroll
    for (int jt = 0; jt < 8; ++jt)
#pragma unroll
        for (int r = 0; r < 4; ++r)
            f16[(16 * wv2 + 4 * h + r) * 136 + 16 * jt + m] = f32_to_bf16(acc[jt][r]);
    __syncthreads();

    // epilogue: comb ft write + el/er (8-lane-group reduce), from C in LDS
    int c = t & 31;   // col quad 4c..4c+3, head = c>>3
    int g = t >> 5;   // nodes 8g..8g+7
    float4 al4 = *(const float4*)(attn_l + 4 * c);
    float4 ar4 = *(const float4*)(attn_r + 4 * c);

#pragma unroll
    for (int j = 0; j < 8; ++j) {
        int n = n0 + 8 * g + j;
        bool ok = n < N;
        uint2 cv = *(const uint2*)(f16 + (8 * g + j) * 136 + 4 * c);
        float f0 = bflo(cv.x), f1 = bfhi(cv.x), f2 = bflo(cv.y), f3 = bfhi(cv.y);
        char* row = comb + (size_t)n * ROWB;
        if (ok) *(uint2*)(row + 8 * c) = cv;
        float p = f0 * al4.x + f1 * al4.y + f2 * al4.z + f3 * al4.w;
        float q = f0 * ar4.x + f1 * ar4.y + f2 * ar4.z + f3 * ar4.w;
#pragma unroll
        for (int off = 1; off < 8; off <<= 1) {
            p += __shfl_xor(p, off);
            q += __shfl_xor(q, off);
        }
        if (ok && (c & 7) == 0) {
            float* ep = (float*)(row + 288);
            ep[c >> 3] = p;
            ep[4 + (c >> 3)] = q;
        }
    }
}

// ---------------- k_agg: one wave/node; 2 edges/step, uint4 gathers -------
__global__ __launch_bounds__(256) void k_agg(
    const char* __restrict__ comb, const float* __restrict__ bias,
    const int* __restrict__ cnt, const u16* __restrict__ ss,
    float* __restrict__ rst, float* __restrict__ yp, int N) {
    __shared__ float ee_lds[4][256];   // per-wave 1KB slice: [edge][head]
    int w = (int)((blockIdx.x * (size_t)blockDim.x + threadIdx.x) >> 6);
    int lane = threadIdx.x & 63;
    int wv = threadIdx.x >> 6;
    if (w >= N) return;

    int sub = lane & 31;
    int p = lane >> 5;
    bool isft = sub < 16;
    bool isy = (sub >= 16) && (sub < 24);
    int head = isft ? (sub >> 2) : (isy ? ((sub - 16) >> 1) : 0);
    int voff = isft ? 16 * sub : (256 + 16 * ((sub - 16) & 1));

    const char* roww = comb + (size_t)w * ROWB;
    float4 er4 = *(const float4*)(roww + 304);

    int deg = min(cnt[w], BSLOT);
    int degp = min((deg + 7) & ~7, BSLOT);
    int beg = w * BSLOT;

    float acc0 = 0.f, acc1 = 0.f, acc2 = 0.f, acc3 = 0.f;
    float acc4 = 0.f, acc5 = 0.f, acc6 = 0.f, acc7 = 0.f;
    float ssum = 0.f;
    float* my_ee = &ee_lds[wv][0];
    const float* eeL = my_ee + 4 * p + head;

#define LOADS(qq, V, Ee)                                        \
    {                                                           \
        int s0_ = __builtin_amdgcn_readlane(my_s, 2 * (qq));    \
        int s1_ = __builtin_amdgcn_readlane(my_s, 2 * (qq) + 1);\
        int s_ = p ? s1_ : s0_;                                 \
        const char* rb_ = comb + (size_t)s_ * ROWB;             \
        V = *(const uint4*)(rb_ + voff);                        \
        Ee = eeL[8 * (qq)];                                     \
    }
#define COMPS(V, Ee)                                            \
    {                                                           \
        ssum += Ee;                                             \
        acc0 = fmaf(Ee, bflo(V.x), acc0);                       \
        acc1 = fmaf(Ee, bfhi(V.x), acc1);                       \
        acc2 = fmaf(Ee, bflo(V.y), acc2);                       \
        acc3 = fmaf(Ee, bfhi(V.y), acc3);                       \
        acc4 = fmaf(Ee, bflo(V.z), acc4);                       \
        acc5 = fmaf(Ee, bfhi(V.z), acc5);                       \
        acc6 = fmaf(Ee, bflo(V.w), acc6);                       \
        acc7 = fmaf(Ee, bfhi(V.w), acc7);                       \
    }
#define LOAD4A(gg)                                              \
    {                                                           \
        int b4_ = 4 * (gg);                                     \
        LOADS(b4_ + 0, va0, ea0); LOADS(b4_ + 1, va1, ea1);     \
        LOADS(b4_ + 2, va2, ea2); LOADS(b4_ + 3, va3, ea3);     \
    }
#define LOAD4B(gg)                                              \
    {                                                           \
        int b4_ = 4 * (gg);                                     \
        LOADS(b4_ + 0, vb0, eb0); LOADS(b4_ + 1, vb1, eb1);     \
        LOADS(b4_ + 2, vb2, eb2); LOADS(b4_ + 3, vb3, eb3);     \
    }
#define COMP4A { COMPS(va0, ea0); COMPS(va1, ea1); COMPS(va2, ea2); COMPS(va3, ea3); }
#define COMP4B { COMPS(vb0, eb0); COMPS(vb1, eb1); COMPS(vb2, eb2); COMPS(vb3, eb3); }

    for (int off = 0; off < degp; off += 64) {
        int cl = min(64, degp - off);   // multiple of 8
        int my_s = (int)ss[beg + off + lane];
        my_s = (off + lane < deg) ? my_s : N;   // sentinel for pad/garbage slots

        // chunk preamble: lane computes its edge's ee for all 4 heads
        {
            const float4 el4 = *(const float4*)(comb + (size_t)my_s * ROWB + 288);
            float4 e4;
            e4.x = el4.x + er4.x;
            e4.y = el4.y + er4.y;
            e4.z = el4.z + er4.z;
            e4.w = el4.w + er4.w;
            float4 ee4;
            ee4.x = __expf(fmaxf(e4.x, NEG_SLOPE * e4.x));
            ee4.y = __expf(fmaxf(e4.y, NEG_SLOPE * e4.y));
            ee4.z = __expf(fmaxf(e4.z, NEG_SLOPE * e4.z));
            ee4.w = __expf(fmaxf(e4.w, NEG_SLOPE * e4.w));
            *(float4*)(my_ee + 4 * lane) = ee4;
        }

        int ngr = cl >> 3;   // groups of 4 steps = 8 edges
        uint4 va0, va1, va2, va3, vb0, vb1, vb2, vb3;
        float ea0, ea1, ea2, ea3, eb0, eb1, eb2, eb3;

        LOAD4A(0);
        int q = 0;
        for (; q + 2 <= ngr; q += 2) {
            LOAD4B(q + 1);
            COMP4A;
            if (q + 2 < ngr) LOAD4A(q + 2);
            COMP4B;
        }
        if (q < ngr) COMP4A;
    }
#undef LOADS
#undef COMPS
#undef LOAD4A
#undef LOAD4B
#undef COMP4A
#undef COMP4B

    // combine the two edge-parity halves
    ssum += __shfl_xor(ssum, 32);
    acc0 += __shfl_xor(acc0, 32);
    acc1 += __shfl_xor(acc1, 32);
    acc2 += __shfl_xor(acc2, 32);
    acc3 += __shfl_xor(acc3, 32);
    acc4 += __shfl_xor(acc4, 32);
    acc5 += __shfl_xor(acc5, 32);
    acc6 += __shfl_xor(acc6, 32);
    acc7 += __shfl_xor(acc7, 32);

    float inv = 1.f / fmaxf(ssum, 1e-9f);
    if (p == 0) {
        if (isft) {
            float4 b0 = *(const float4*)(bias + 8 * sub);
            float4 b1 = *(const float4*)(bias + 8 * sub + 4);
            float4 o0 = make_float4(fmaf(acc0, inv, b0.x), fmaf(acc1, inv, b0.y),
                                    fmaf(acc2, inv, b0.z), fmaf(acc3, inv, b0.w));
            float4 o1 = make_float4(fmaf(acc4, inv, b1.x), fmaf(acc5, inv, b1.y),
                                    fmaf(acc6, inv, b1.z), fmaf(acc7, inv, b1.w));
            *(float4*)(rst + (size_t)w * 128 + 8 * sub) = o0;
            *(float4*)(rst + (size_t)w * 128 + 8 * sub + 4) = o1;
        } else if (isy) {
            int yi = sub - 16;
            int hh = yi >> 1, hf = yi & 1;
            float4 o0 = make_float4(acc0 * inv, acc1 * inv, acc2 * inv, acc3 * inv);
            float4 o1 = make_float4(acc4 * inv, acc5 * inv, acc6 * inv, acc7 * inv);
            *(float4*)(yp + (size_t)w * 64 + 16 * hh + 8 * hf) = o0;
            *(float4*)(yp + (size_t)w * 64 + 16 * hh + 8 * hf + 4) = o1;
        }
    }
}

extern "C" void kernel_launch(void* const* d_in, const int* in_sizes, int n_in,
                              void* d_out, int out_size, void* d_ws, size_t ws_size,
                              hipStream_t stream) {
    const float* feat   = (const float*)d_in[0];
    const float* y      = (const float*)d_in[1];
    const float* fc_w   = (const float*)d_in[2];
    const float* attn_l = (const float*)d_in[3];
    const float* attn_r = (const float*)d_in[4];
    const float* bias   = (const float*)d_in[5];
    const int*   src    = (const int*)d_in[6];
    const int*   dst    = (const int*)d_in[7];

    const int N = in_sizes[0] / 128;  // FIN = 128
    const int E = in_sizes[6];

    char* comb = (char*)d_ws;                            // (N+1) * 320 B
    int* cnt = (int*)(comb + (size_t)(N + 1) * ROWB);    // N ints
    int* subCursor = cnt + N;                            // NSUBMAX ints
    u16* ss = (u16*)(subCursor + NSUBMAX);               // BSLOT*N u16
    u32* subQ = (u32*)(ss + (size_t)BSLOT * N);          // nSub * SUBCAP u32

    float* rst = (float*)d_out;                          // N*128
    float* yp = rst + (size_t)N * 128;                   // N*64

    const int nSub = (N + 255) >> SUBSHIFT;              // 196 for N=50000
    const int projB = (N + 63) / 64;
    const int binAB = (E + 4095) / 4096;

    (void)hipMemsetAsync(subCursor, 0, NSUBMAX * sizeof(int), stream);
    k_binA2<<<dim3(binAB), dim3(256), 0, stream>>>(
        src, dst, subQ, subCursor, nSub, E);
    k_fused<<<dim3(nSub + projB), dim3(256), 0, stream>>>(
        feat, fc_w, y, attn_l, attn_r, comb, subQ, subCursor, cnt, ss, N, nSub);
    k_agg<<<dim3(((size_t)N * 64 + 255) / 256), dim3(256), 0, stream>>>(
        comb, bias, cnt, ss, rst, yp, N);
}